// Round 11
// baseline (80.274 us; speedup 1.0000x reference)
//
#include <hip/hip_runtime.h>

// RNNT (Transducer) alpha-recursion loss, forward, mean reduction.
// B=4, T=512, U=100 (U+1=101 cols), V=1024, fp32.
//
// Linear-domain DP (recurrence linear over (+,x)):
//   a[t][u] = a[t-1][u]*fB + a[t][u-1]*fE
// R11 = R10's proven gather/DP bodies fused into ONE kernel with
// producer->consumer overlap. R8's overlap failed because the consumer paid
// a cross-XCD acquire load per 16-row window (39x ~0.5us on the chain).
// Now: flags per 64-row SUPER-window (10/batch) + a cached high-water mark
// so steady-state checks are register compares; ~10 remote loads per batch.
//
//  Blocks 4..615 (producers): block 4+pid covers rows 4*(pid>>2)+wave of
//    batch pid&3 (low rows dispatched first). Rect-masked scatter-gather of
//    blank (v=0) / emit (v=label), per-diagonal mean-normalized (m_r from a
//    64-lane shfl reduce, stored to g_m), exp2 -> f64 pairs:
//      g_P1[r][l] = {fB(u0), fE(u0-1)}  (A-update), g_P2 = {fB(u1), fE(u0)}
//    Rows r < smax signal g_done[b][r>>6] with agent-scope release.
//  Blocks 0..3 (consumers, wave 0): R10's DP verbatim; lane l owns columns
//    u=2l,2l+1; left neighbor via DPP wave_shr:1 on both halves of the
//    double; W=12-row groups, modulo-3 pipeline; no in-loop rescale
//    (per-diagonal normalization bounds f64 range); before each LOADG,
//    WAITROWS checks the super-window flags (cached -> mostly free).
//  Last consumer reduces g_ps -> out, resets g_done/g_ctr (replay-safe:
//  all signaling producers are provably done when the last consumer is).

constexpr int B = 4, T = 512, U = 100, Up1 = 101, V = 1024;
constexpr int DIAGS = T + U;       // 612
constexpr int W = 12;              // DP steps / rows per load group
constexpr int NSW = (DIAGS + 63) / 64;   // 10 super-windows of 64 rows
constexpr float LOG2E = 1.44269504088896340736f;
constexpr float LN2 = 0.69314718055994530942f;

__device__ double2 g_P1[(size_t)B * DIAGS * 64];   // {x=fB(u0), z=fE(u0-1)}
__device__ double2 g_P2[(size_t)B * DIAGS * 64];   // {y=fB(u1), w=fE(u0)}
__device__ float g_m[(size_t)B * DIAGS];           // per-diagonal log2 scale
__device__ int g_done[B][NSW];     // rows signaled per super-window
__device__ float g_ps[B];          // per-sample log2(alpha_final)
__device__ int g_ctr = 0;

__device__ __forceinline__ int clampi(int x, int lo, int hi) {
  return x < lo ? lo : (x > hi ? hi : x);
}
__device__ __forceinline__ float fexp2(float x) {
  float r; asm("v_exp_f32 %0, %1" : "=v"(r) : "v"(x)); return r;
}
__device__ __forceinline__ float flog2(float x) {
  float r; asm("v_log_f32 %0, %1" : "=v"(r) : "v"(x)); return r;
}
// whole-wave shift by 1 on a double: lane l receives lane l-1's value
// (lane 0 keeps its own; its left factor is 0 so it never contributes)
__device__ __forceinline__ double wave_shr1_f64(double x) {
  int hi = __double2hiint(x), lo = __double2loint(x);
  hi = __builtin_amdgcn_update_dpp(hi, hi, 0x138 /*WF_SR1*/, 0xF, 0xF, false);
  lo = __builtin_amdgcn_update_dpp(lo, lo, 0x138 /*WF_SR1*/, 0xF, 0xF, false);
  return __hiloint2double(hi, lo);
}

__global__ __launch_bounds__(256, 1)
void rnnt_fused(const float* __restrict__ logits,
                const int* __restrict__ labels,
                const int* __restrict__ logit_len,
                const int* __restrict__ label_len,
                float* __restrict__ out) {
  const int lane = threadIdx.x & 63;

  // ================= producers (blocks 4..615) =================
  if (blockIdx.x >= B) {
    const int pid = blockIdx.x - B;
    const int b = pid & 3;
    const int r = (pid >> 2) * 4 + (threadIdx.x >> 6);   // anti-diagonal row
    const int Tb = clampi(logit_len[b], 1, T);
    const int Ub = clampi(label_len[b], 1, U);
    const int smax = Tb - 1 + Ub;

    if (r <= smax) {
      const float* lg = logits + (size_t)b * T * Up1 * V;
      const int u0 = 2 * lane, u1 = u0 + 1;
      float vx = 0.f, vy = 0.f, vz = 0.f, vw = 0.f;
      bool bx = false, by = false, bz = false, bw = false;

      int tx = r - u0;                                   // blank[tx][u0]
      if (u0 <= Ub && tx >= 0 && tx <= Tb - 1) {
        vx = LOG2E * lg[((size_t)tx * Up1 + u0) * V]; bx = true;
      }
      int ty = r - u1;                                   // blank[ty][u1]
      if (u1 <= Ub && ty >= 0 && ty <= Tb - 1) {
        vy = LOG2E * lg[((size_t)ty * Up1 + u1) * V]; by = true;
      }
      int tz = r - u0 + 1;                               // emit[tz][u0-1]
      if (u0 >= 1 && u0 <= Ub && tz >= 0 && tz <= Tb - 1) {
        int lab = clampi(labels[b * U + (u0 - 1)], 0, V - 1);
        vz = LOG2E * lg[((size_t)tz * Up1 + (u0 - 1)) * V + lab]; bz = true;
      }
      int tw = r - u0;                                   // emit[tw][u0]
      if (u0 <= Ub - 1 && tw >= 0 && tw <= Tb - 1) {
        int lab = clampi(labels[b * U + u0], 0, V - 1);
        vw = LOG2E * lg[((size_t)tw * Up1 + u0) * V + lab]; bw = true;
      }

      // per-diagonal mean log2-factor (wave-uniform integer)
      float s = (bx ? vx : 0.f) + (by ? vy : 0.f) + (bz ? vz : 0.f) + (bw ? vw : 0.f);
      float c = (float)((int)bx + (int)by + (int)bz + (int)bw);
      for (int off = 32; off; off >>= 1) {
        s += __shfl_xor(s, off, 64);
        c += __shfl_xor(c, off, 64);
      }
      float m = (c > 0.f) ? rintf(s / c) : 0.f;

      const size_t idx = ((size_t)b * DIAGS + r) * 64 + lane;
      g_P1[idx] = make_double2(bx ? (double)fexp2(vx - m) : 0.0,
                               bz ? (double)fexp2(vz - m) : 0.0);
      g_P2[idx] = make_double2(by ? (double)fexp2(vy - m) : 0.0,
                               bw ? (double)fexp2(vw - m) : 0.0);
      if (lane == 0) g_m[(size_t)b * DIAGS + r] = m;

      // signal only rows the consumer waits on (r < smax); release orders
      // the stores above before the count becomes visible
      if (lane == 0 && r < smax)
        __hip_atomic_fetch_add(&g_done[b][r >> 6], 1, __ATOMIC_RELEASE,
                               __HIP_MEMORY_SCOPE_AGENT);
    }
    return;
  }

  // ================= consumers (blocks 0..3, wave 0) =================
  if (threadIdx.x >= 64) return;
  const int b = blockIdx.x;
  const int Tb = clampi(logit_len[b], 1, T);
  const int Ub = clampi(label_len[b], 1, U);
  const int smax = Tb - 1 + Ub;        // diagonal (= step) of the answer cell
  const double2* P1 = g_P1 + (size_t)b * DIAGS * 64;
  const double2* P2 = g_P2 + (size_t)b * DIAGS * 64;

  double A = (lane == 0) ? 1.0 : 0.0;  // alpha[0][0] = 1 (diag 0 done)
  double Bc = 0.0;
  int sw_ok = -1;                      // highest fully-available super-window

  double2 a1[W], a2[W], b1[W], b2[W], c1[W], c2[W];

  // ensure rows 0..min(lastrow, smax-1) are visible; cached high-water mark
  // makes the steady-state cost a register compare
#define WAITROWS(lastrow)                                                      \
  {                                                                            \
    int lr_ = (lastrow); if (lr_ > smax - 1) lr_ = smax - 1;                   \
    int sw_ = lr_ >> 6;                                                        \
    while (sw_ > sw_ok) {                                                      \
      int nsw_ = sw_ok + 1;                                                    \
      int need_ = smax - nsw_ * 64; if (need_ > 64) need_ = 64;                \
      if (need_ <= 0) { sw_ok = nsw_; continue; }                              \
      if (__hip_atomic_load(&g_done[b][nsw_], __ATOMIC_ACQUIRE,                \
                            __HIP_MEMORY_SCOPE_AGENT) >= need_)                \
        sw_ok = nsw_;                                                          \
      else                                                                     \
        __builtin_amdgcn_s_sleep(2);                                           \
    }                                                                          \
  }

  // group g holds rows g*W .. g*W+W-1 (step s consumes row s-1)
#define LOADG(u, v, grp)                                                       \
  {                                                                            \
    WAITROWS((grp) * W + W - 1);                                               \
    int base_ = (grp) * W;                                                     \
    _Pragma("unroll")                                                          \
    for (int j_ = 0; j_ < W; ++j_) {                                           \
      int r_ = base_ + j_; if (r_ > DIAGS - 1) r_ = DIAGS - 1;                 \
      u[j_] = P1[(size_t)r_ * 64 + lane];                                      \
      v[j_] = P2[(size_t)r_ * 64 + lane];                                      \
    }                                                                          \
  }

#define STEPS(u, v, grp)                                                       \
  {                                                                            \
    int sb_ = (grp) * W + 1;                                                   \
    _Pragma("unroll")                                                          \
    for (int j_ = 0; j_ < W; ++j_) {                                           \
      int s_ = sb_ + j_;                                                       \
      if (s_ <= smax) {                                                        \
        double shrB_ = wave_shr1_f64(Bc);                                      \
        double na_ = fma(A, u[j_].x, shrB_ * u[j_].y);                         \
        double nb_ = fma(Bc, v[j_].x, A * v[j_].y);                            \
        A = na_; Bc = nb_;                                                     \
      }                                                                        \
    }                                                                          \
  }

  const int NW = (smax + W - 1) / W;   // windows covering steps 1..smax
  LOADG(a1, a2, 0);
  if (NW > 1) LOADG(b1, b2, 1);
  for (int k = 0; k < NW; k += 3) {
    if (k + 2 < NW) LOADG(c1, c2, k + 2);
    STEPS(a1, a2, k);
    if (k + 1 < NW) {
      if (k + 3 < NW) LOADG(a1, a2, k + 3);
      STEPS(b1, b2, k + 1);
      if (k + 2 < NW) {
        if (k + 4 < NW) LOADG(b1, b2, k + 4);
        STEPS(c1, c2, k + 2);
      }
    }
  }

  // answer cell (Tb-1, Ub) was produced at step smax (the final step)
  const int ansLane = Ub >> 1;
  double va = __shfl(A, ansLane, 64);
  double vb = __shfl(Bc, ansLane, 64);
  double v = (Ub & 1) ? vb : va;
  int ev = ((__double2hiint(v) >> 20) & 0x7ff) - 1023;
  double mant = ldexp(v, -ev);

  // accumulated per-diagonal scales: steps 1..smax consumed rows 0..smax-1
  // (all covered by the WAITROWS acquires above)
  float msum = 0.f;
  for (int r = lane; r <= smax - 1; r += 64)
    msum += g_m[(size_t)b * DIAGS + r];
  for (int off = 32; off; off >>= 1) msum += __shfl_xor(msum, off, 64);

  float lg2 = (float)ev + flog2((float)mant) + msum;

  if (lane == 0) {
    __hip_atomic_store(&g_ps[b], lg2, __ATOMIC_RELEASE, __HIP_MEMORY_SCOPE_AGENT);
    int old = __hip_atomic_fetch_add(&g_ctr, 1, __ATOMIC_ACQ_REL,
                                     __HIP_MEMORY_SCOPE_AGENT);
    if (old == B - 1) {
      // all consumers done => every signaling producer's add has been
      // observed => resetting flags cannot race with producers
      float s = 0.0f;
      for (int i = 0; i < B; ++i)
        s += __hip_atomic_load(&g_ps[i], __ATOMIC_ACQUIRE, __HIP_MEMORY_SCOPE_AGENT);
      out[0] = -s * (LN2 / B);
      for (int i = 0; i < B; ++i)
        for (int w = 0; w < NSW; ++w)
          __hip_atomic_store(&g_done[i][w], 0, __ATOMIC_RELAXED,
                             __HIP_MEMORY_SCOPE_AGENT);
      __hip_atomic_store(&g_ctr, 0, __ATOMIC_RELAXED, __HIP_MEMORY_SCOPE_AGENT);
    }
  }
#undef WAITROWS
#undef LOADG
#undef STEPS
}

extern "C" void kernel_launch(void* const* d_in, const int* in_sizes, int n_in,
                              void* d_out, int out_size, void* d_ws, size_t ws_size,
                              hipStream_t stream) {
  const float* logits = (const float*)d_in[0];
  const int* labels = (const int*)d_in[1];
  const int* logit_len = (const int*)d_in[2];
  const int* label_len = (const int*)d_in[3];
  float* out = (float*)d_out;

  hipLaunchKernelGGL(rnnt_fused, dim3(B + DIAGS), dim3(256), 0, stream,
                     logits, labels, logit_len, label_len, out);
}

// Round 12
// 37.269 us; speedup vs baseline: 2.1539x; 2.1539x over previous
//
#include <hip/hip_runtime.h>

// RNNT (Transducer) alpha-recursion loss, forward, mean reduction.
// B=4, T=512, U=100 (U+1=101 cols), V=1024, fp32.
//
// Linear-domain DP (recurrence linear over (+,x)):
//   a[t][u] = a[t-1][u]*fB + a[t][u-1]*fE
// R12: 2-STEP FUSION. Two consecutive diagonal updates compose into one
// macro-step with 2-wide lane coupling (reachable with wave_shr:1 only):
//   A'' = cAA*A + cAB*shrB + cA2*shrA
//   B'' = cBB*B + cBA*A   + cB1*shrB
// with per-lane coefficients precomputed by the WIDE gather (idle waves):
//   cAA=x2*x1, cAB=x2*z1+z2*y1[l-1], cA2=z2*w1[l-1],
//   cBA=w2*x1+y2*w1, cB1=w2*z1, cBB=y2*y1     (row1=step s, row2=step s+1)
// DP: 306 macro-steps instead of 612 steps; per macro: 4 DPP + 6 f64 ops +
// 3x b128 (~38cy issue / 2 diagonals vs ~50). f64 state, per-MACRO
// normalization (m1+m2, same f64-range argument as R10 -> no in-loop
// rescale). Odd smax: one raw-factor single step from g_L1/g_L2.
// Two-kernel structure (overlap refuted in R8/R11).

constexpr int B = 4, T = 512, U = 100, Up1 = 101, V = 1024;
constexpr int DIAGS = T + U;       // 612
constexpr int MM = DIAGS / 2;      // 306 macro rows
constexpr int W = 9;               // macro-steps per load group (mod-3 pipe)
constexpr float LOG2E = 1.44269504088896340736f;
constexpr float LN2 = 0.69314718055994530942f;

__device__ double2 g_C1[(size_t)B * MM * 64];   // {cAA, cAB}
__device__ double2 g_C2[(size_t)B * MM * 64];   // {cA2, cBA}
__device__ double2 g_C3[(size_t)B * MM * 64];   // {cB1, cBB}
__device__ double2 g_L1[B * 64];                // odd tail {x, z}
__device__ double2 g_L2[B * 64];                // odd tail {y, w}
__device__ float g_mm[B * MM];                  // per-macro log2 scale
__device__ float g_lastm[B];                    // odd-tail log2 scale
__device__ float g_ps[B];                       // per-sample log2(alpha)
__device__ int g_ctr = 0;

__device__ __forceinline__ int clampi(int x, int lo, int hi) {
  return x < lo ? lo : (x > hi ? hi : x);
}
__device__ __forceinline__ float fexp2(float x) {
  float r; asm("v_exp_f32 %0, %1" : "=v"(r) : "v"(x)); return r;
}
__device__ __forceinline__ float flog2(float x) {
  float r; asm("v_log_f32 %0, %1" : "=v"(r) : "v"(x)); return r;
}
// whole-wave shift by 1 on a double: lane l receives lane l-1's value
// (lane 0 keeps its own; its coefficients for shifted terms are 0)
__device__ __forceinline__ double wave_shr1_f64(double x) {
  int hi = __double2hiint(x), lo = __double2loint(x);
  hi = __builtin_amdgcn_update_dpp(hi, hi, 0x138 /*WF_SR1*/, 0xF, 0xF, false);
  lo = __builtin_amdgcn_update_dpp(lo, lo, 0x138 /*WF_SR1*/, 0xF, 0xF, false);
  return __hiloint2double(hi, lo);
}

__global__ __launch_bounds__(256) void gather_kernel(const float* __restrict__ logits,
                                                     const int* __restrict__ labels,
                                                     const int* __restrict__ logit_len,
                                                     const int* __restrict__ label_len) {
  const int b = blockIdx.y;
  const int mr = blockIdx.x * 4 + (threadIdx.x >> 6);   // macro row
  const int l = threadIdx.x & 63;
  const int Tb = clampi(logit_len[b], 1, T);
  const int Ub = clampi(label_len[b], 1, U);
  const int smax = Tb - 1 + Ub;
  const int M = smax >> 1, odd = smax & 1;
  if (mr > M || mr >= MM) return;
  if (mr == M && !odd) return;

  const float* lg = logits + (size_t)b * T * Up1 * V;
  const int u0 = 2 * l, u1 = u0 + 1;
  int labz = 0, labw = 0;
  if (u0 >= 1 && u0 <= U) labz = clampi(labels[b * U + (u0 - 1)], 0, V - 1);
  if (u0 < U)             labw = clampi(labels[b * U + u0], 0, V - 1);

  // factors of one staged row r (normalized by rounded row-mean m)
#define FACTORS(r, fx, fy, fz, fw, m)                                          \
  {                                                                            \
    float vx = 0.f, vy = 0.f, vz = 0.f, vw = 0.f;                              \
    bool bx = false, by = false, bz = false, bw = false;                       \
    int tx = (r) - u0;                                                         \
    if (u0 <= Ub && tx >= 0 && tx <= Tb - 1) {                                 \
      vx = LOG2E * lg[((size_t)tx * Up1 + u0) * V]; bx = true;                 \
    }                                                                          \
    int ty = (r) - u1;                                                         \
    if (u1 <= Ub && ty >= 0 && ty <= Tb - 1) {                                 \
      vy = LOG2E * lg[((size_t)ty * Up1 + u1) * V]; by = true;                 \
    }                                                                          \
    int tz = (r) - u0 + 1;                                                     \
    if (u0 >= 1 && u0 <= Ub && tz >= 0 && tz <= Tb - 1) {                      \
      vz = LOG2E * lg[((size_t)tz * Up1 + (u0 - 1)) * V + labz]; bz = true;    \
    }                                                                          \
    int tw = (r) - u0;                                                         \
    if (u0 <= Ub - 1 && tw >= 0 && tw <= Tb - 1) {                             \
      vw = LOG2E * lg[((size_t)tw * Up1 + u0) * V + labw]; bw = true;          \
    }                                                                          \
    float s_ = (bx ? vx : 0.f) + (by ? vy : 0.f) + (bz ? vz : 0.f) +           \
               (bw ? vw : 0.f);                                                \
    float c_ = (float)((int)bx + (int)by + (int)bz + (int)bw);                 \
    for (int off = 32; off; off >>= 1) {                                       \
      s_ += __shfl_xor(s_, off, 64);                                           \
      c_ += __shfl_xor(c_, off, 64);                                           \
    }                                                                          \
    m = (c_ > 0.f) ? rintf(s_ / c_) : 0.f;                                     \
    fx = bx ? fexp2(vx - m) : 0.f;                                             \
    fy = by ? fexp2(vy - m) : 0.f;                                             \
    fz = bz ? fexp2(vz - m) : 0.f;                                             \
    fw = bw ? fexp2(vw - m) : 0.f;                                             \
  }

  if (mr < M) {
    float x1, y1, z1, w1, m1; FACTORS(2 * mr, x1, y1, z1, w1, m1);
    float x2, y2, z2, w2, m2; FACTORS(2 * mr + 1, x2, y2, z2, w2, m2);
    float y1n = __shfl_up(y1, 1, 64);       // row1 factors of lane l-1
    float w1n = __shfl_up(w1, 1, 64);       // (lane 0: z2==0 masks them)
    double X1 = x1, Y1 = y1, Z1 = z1, W1 = w1;
    double X2 = x2, Y2 = y2, Z2 = z2, W2 = w2;
    double cAA = X2 * X1;
    double cAB = X2 * Z1 + Z2 * (double)y1n;
    double cA2 = Z2 * (double)w1n;
    double cBA = W2 * X1 + Y2 * W1;
    double cB1 = W2 * Z1;
    double cBB = Y2 * Y1;
    const size_t idx = ((size_t)b * MM + mr) * 64 + l;
    g_C1[idx] = make_double2(cAA, cAB);
    g_C2[idx] = make_double2(cA2, cBA);
    g_C3[idx] = make_double2(cB1, cBB);
    if (l == 0) g_mm[b * MM + mr] = m1 + m2;
  } else {                                  // mr == M && odd: raw tail row
    float x, y, z, w, m; FACTORS(smax - 1, x, y, z, w, m);
    g_L1[b * 64 + l] = make_double2((double)x, (double)z);
    g_L2[b * 64 + l] = make_double2((double)y, (double)w);
    if (l == 0) g_lastm[b] = m;
  }
#undef FACTORS
}

__global__ __launch_bounds__(64, 1)
void dp_kernel(const int* __restrict__ logit_len,
               const int* __restrict__ label_len,
               float* __restrict__ out) {
  const int b = blockIdx.x;
  const int lane = threadIdx.x;
  const int Tb = clampi(logit_len[b], 1, T);
  const int Ub = clampi(label_len[b], 1, U);
  const int smax = Tb - 1 + Ub;
  const int M = smax >> 1, odd = smax & 1;
  const double2* C1 = g_C1 + (size_t)b * MM * 64;
  const double2* C2 = g_C2 + (size_t)b * MM * 64;
  const double2* C3 = g_C3 + (size_t)b * MM * 64;

  double A = (lane == 0) ? 1.0 : 0.0;   // alpha[0][0] = 1 (diag 0 done)
  double Bc = 0.0;

  double2 a1[W], a2[W], a3[W], b1_[W], b2_[W], b3_[W], c1_[W], c2_[W], c3_[W];

#define LOADG(p, q, s, grp)                                                    \
  {                                                                            \
    int base_ = (grp) * W;                                                     \
    _Pragma("unroll")                                                          \
    for (int j_ = 0; j_ < W; ++j_) {                                           \
      int m_ = base_ + j_; if (m_ > MM - 1) m_ = MM - 1;                       \
      p[j_] = C1[(size_t)m_ * 64 + lane];                                      \
      q[j_] = C2[(size_t)m_ * 64 + lane];                                      \
      s[j_] = C3[(size_t)m_ * 64 + lane];                                      \
    }                                                                          \
  }

#define STEPS(p, q, s, grp)                                                    \
  {                                                                            \
    _Pragma("unroll")                                                          \
    for (int j_ = 0; j_ < W; ++j_) {                                           \
      int m_ = (grp) * W + j_;                                                 \
      if (m_ < M) {                                                            \
        double shrA_ = wave_shr1_f64(A);                                       \
        double shrB_ = wave_shr1_f64(Bc);                                      \
        double na_ = fma(A, p[j_].x, fma(shrB_, p[j_].y, shrA_ * q[j_].x));    \
        double nb_ = fma(Bc, s[j_].y, fma(A, q[j_].y, shrB_ * s[j_].x));       \
        A = na_; Bc = nb_;                                                     \
      }                                                                        \
    }                                                                          \
  }

  const int NW = (M + W - 1) / W;
  if (NW > 0) {
    LOADG(a1, a2, a3, 0);
    if (NW > 1) LOADG(b1_, b2_, b3_, 1);
    for (int k = 0; k < NW; k += 3) {
      if (k + 2 < NW) LOADG(c1_, c2_, c3_, k + 2);
      STEPS(a1, a2, a3, k);
      if (k + 1 < NW) {
        if (k + 3 < NW) LOADG(a1, a2, a3, k + 3);
        STEPS(b1_, b2_, b3_, k + 1);
        if (k + 2 < NW) {
          if (k + 4 < NW) LOADG(b1_, b2_, b3_, k + 4);
          STEPS(c1_, c2_, c3_, k + 2);
        }
      }
    }
  }
  if (odd) {                              // single raw step smax
    double2 L1 = g_L1[b * 64 + lane];     // {x, z}
    double2 L2 = g_L2[b * 64 + lane];     // {y, w}
    double shrB = wave_shr1_f64(Bc);
    double na = fma(A, L1.x, shrB * L1.y);
    double nb = fma(Bc, L2.x, A * L2.y);
    A = na; Bc = nb;
  }

  // answer cell (Tb-1, Ub) produced at step smax
  const int ansLane = Ub >> 1;
  double va = __shfl(A, ansLane, 64);
  double vb = __shfl(Bc, ansLane, 64);
  double v = (Ub & 1) ? vb : va;
  int ev = ((__double2hiint(v) >> 20) & 0x7ff) - 1023;
  double mant = ldexp(v, -ev);

  float msum = 0.f;
  for (int m = lane; m < M; m += 64) msum += g_mm[b * MM + m];
  for (int off = 32; off; off >>= 1) msum += __shfl_xor(msum, off, 64);
  if (odd) msum += g_lastm[b];

  float lg2 = (float)ev + flog2((float)mant) + msum;

  if (lane == 0) {
    __hip_atomic_store(&g_ps[b], lg2, __ATOMIC_RELEASE, __HIP_MEMORY_SCOPE_AGENT);
    int old = __hip_atomic_fetch_add(&g_ctr, 1, __ATOMIC_ACQ_REL,
                                     __HIP_MEMORY_SCOPE_AGENT);
    if (old == B - 1) {
      float s = 0.0f;
      for (int i = 0; i < B; ++i)
        s += __hip_atomic_load(&g_ps[i], __ATOMIC_ACQUIRE, __HIP_MEMORY_SCOPE_AGENT);
      out[0] = -s * (LN2 / B);
      __hip_atomic_store(&g_ctr, 0, __ATOMIC_RELAXED, __HIP_MEMORY_SCOPE_AGENT);
    }
  }
#undef LOADG
#undef STEPS
}

extern "C" void kernel_launch(void* const* d_in, const int* in_sizes, int n_in,
                              void* d_out, int out_size, void* d_ws, size_t ws_size,
                              hipStream_t stream) {
  const float* logits = (const float*)d_in[0];
  const int* labels = (const int*)d_in[1];
  const int* logit_len = (const int*)d_in[2];
  const int* label_len = (const int*)d_in[3];
  float* out = (float*)d_out;

  hipLaunchKernelGGL(gather_kernel, dim3((MM + 3) / 4, B), dim3(256), 0, stream,
                     logits, labels, logit_len, label_len);
  hipLaunchKernelGGL(dp_kernel, dim3(B), dim3(64), 0, stream,
                     logit_len, label_len, out);
}

// Round 13
// 34.896 us; speedup vs baseline: 2.3004x; 1.0680x over previous
//
#include <hip/hip_runtime.h>

// RNNT (Transducer) alpha-recursion loss, forward, mean reduction.
// B=4, T=512, U=100 (U+1=101 cols), V=1024, fp32.
//
// Linear-domain DP (recurrence linear over (+,x)):
//   a[t][u] = a[t-1][u]*fB + a[t][u-1]*fE
// R13: 4-STEP FUSION = composition of two VERIFIED 2-step maps (R12).
// 2-step map form (per lane, X1 = subscript at lane l-1):
//   A' = p*A + q*B1 + r*A1 ;  B' = s*B + t*A + u*B1
// Composition N(M(state)) (M = diagonals 4m,4m+1; N = 4m+2,4m+3):
//   A'' = dA*A + dB1*B1 + dA1*A1 + dB2*B2 + dA2*A2
//   B'' = eB*B + eA*A + eB1*B1 + eA1*A1 + eB2*B2
//   dA=Np*Mp; dB1=Np*Mq+Nq*Ms1; dA1=Np*Mr+Nq*Mt1+Nr*Mp1;
//   dB2=Nq*Mu1+Nr*Mq1; dA2=Nr*Mr1; eB=Ns*Ms; eA=Ns*Mt+Nt*Mp;
//   eB1=Ns*Mu+Nt*Mq+Nu*Ms1; eA1=Nt*Mr+Nu*Mt1; eB2=Nu*Mu1
// (identity checks: N=I -> M, M=I -> N; lane-0/1 cross terms are exact 0).
// DP macro: 8 DPP (shr1 + chained shr2 of A,B) + 10 f64 FMA + 5 b128
// (~66cy / 4 diagonals vs R12's 76); 153 dependent iterations (vs 306).
// Whole-macro normalization by shared rounded mean m (factors exp2(v-m),
// scale 4m per macro accumulated post-loop). Tail rem=smax&3 raw steps.
// Two-kernel structure (overlap refuted R8/R11).

constexpr int B = 4, T = 512, U = 100, Up1 = 101, V = 1024;
constexpr int DIAGS = T + U;        // 612
constexpr int MM4 = (DIAGS + 3) / 4;  // 153 macro rows (4 diagonals each)
constexpr int W = 5;                // macro-steps per load group (mod-3 pipe)
constexpr float LOG2E = 1.44269504088896340736f;
constexpr float LN2 = 0.69314718055994530942f;

__device__ double2 g_D1[(size_t)B * MM4 * 64];  // {dA,  dB1}
__device__ double2 g_D2[(size_t)B * MM4 * 64];  // {dA1, dB2}
__device__ double2 g_D3[(size_t)B * MM4 * 64];  // {dA2, eB }
__device__ double2 g_D4[(size_t)B * MM4 * 64];  // {eA,  eB1}
__device__ double2 g_D5[(size_t)B * MM4 * 64];  // {eA1, eB2}
__device__ double2 g_L1[3][B * 64];             // tail raw {x,z}
__device__ double2 g_L2[3][B * 64];             // tail raw {y,w}
__device__ float g_mm[B * MM4];                 // per-macro log2 scale (=4m)
__device__ float g_lastm[B][3];                 // tail per-row scales
__device__ float g_ps[B];                       // per-sample log2(alpha)
__device__ int g_ctr = 0;

__device__ __forceinline__ int clampi(int x, int lo, int hi) {
  return x < lo ? lo : (x > hi ? hi : x);
}
__device__ __forceinline__ float fexp2(float x) {
  float r; asm("v_exp_f32 %0, %1" : "=v"(r) : "v"(x)); return r;
}
__device__ __forceinline__ float flog2(float x) {
  float r; asm("v_log_f32 %0, %1" : "=v"(r) : "v"(x)); return r;
}
// whole-wave shift by 1 on a double: lane l receives lane l-1's value
// (lane 0 keeps its own; its coefficients for shifted terms are exact 0)
__device__ __forceinline__ double wave_shr1_f64(double x) {
  int hi = __double2hiint(x), lo = __double2loint(x);
  hi = __builtin_amdgcn_update_dpp(hi, hi, 0x138 /*WF_SR1*/, 0xF, 0xF, false);
  lo = __builtin_amdgcn_update_dpp(lo, lo, 0x138 /*WF_SR1*/, 0xF, 0xF, false);
  return __hiloint2double(hi, lo);
}

__global__ __launch_bounds__(256) void gather_kernel(const float* __restrict__ logits,
                                                     const int* __restrict__ labels,
                                                     const int* __restrict__ logit_len,
                                                     const int* __restrict__ label_len) {
  const int b = blockIdx.y;
  const int mr = blockIdx.x * 4 + (threadIdx.x >> 6);   // macro row index
  const int l = threadIdx.x & 63;
  const int Tb = clampi(logit_len[b], 1, T);
  const int Ub = clampi(label_len[b], 1, U);
  const int smax = Tb - 1 + Ub;
  const int Mq = smax >> 2, rem = smax & 3;
  if (mr > Mq) return;

  const float* lg = logits + (size_t)b * T * Up1 * V;
  const int u0 = 2 * l, u1 = u0 + 1;
  int labz = 0, labw = 0;
  if (u0 >= 1 && u0 <= U) labz = clampi(labels[b * U + (u0 - 1)], 0, V - 1);
  if (u0 < U)             labw = clampi(labels[b * U + u0], 0, V - 1);

  if (mr == Mq) {                       // tail rows 4Mq+j, j<rem (raw factors)
    for (int j = 0; j < rem; ++j) {
      int r = 4 * Mq + j;
      float vx = 0.f, vy = 0.f, vz = 0.f, vw = 0.f;
      bool bx = false, by = false, bz = false, bw = false;
      int tx = r - u0;
      if (u0 <= Ub && tx >= 0 && tx <= Tb - 1) { vx = LOG2E * lg[((size_t)tx * Up1 + u0) * V]; bx = true; }
      int ty = r - u1;
      if (u1 <= Ub && ty >= 0 && ty <= Tb - 1) { vy = LOG2E * lg[((size_t)ty * Up1 + u1) * V]; by = true; }
      int tz = r - u0 + 1;
      if (u0 >= 1 && u0 <= Ub && tz >= 0 && tz <= Tb - 1) { vz = LOG2E * lg[((size_t)tz * Up1 + (u0 - 1)) * V + labz]; bz = true; }
      int tw = r - u0;
      if (u0 <= Ub - 1 && tw >= 0 && tw <= Tb - 1) { vw = LOG2E * lg[((size_t)tw * Up1 + u0) * V + labw]; bw = true; }
      float s_ = (bx ? vx : 0.f) + (by ? vy : 0.f) + (bz ? vz : 0.f) + (bw ? vw : 0.f);
      float c_ = (float)((int)bx + (int)by + (int)bz + (int)bw);
      for (int off = 32; off; off >>= 1) { s_ += __shfl_xor(s_, off, 64); c_ += __shfl_xor(c_, off, 64); }
      float m = (c_ > 0.f) ? rintf(s_ / c_) : 0.f;
      g_L1[j][b * 64 + l] = make_double2(bx ? (double)fexp2(vx - m) : 0.0,
                                         bz ? (double)fexp2(vz - m) : 0.0);
      g_L2[j][b * 64 + l] = make_double2(by ? (double)fexp2(vy - m) : 0.0,
                                         bw ? (double)fexp2(vw - m) : 0.0);
      if (l == 0) g_lastm[b][j] = m;
    }
    return;
  }

  // ---- full macro: rows 4mr .. 4mr+3 ----
  float vx[4], vy[4], vz[4], vw[4];
  bool bx[4], by[4], bz[4], bw[4];
#pragma unroll
  for (int k = 0; k < 4; ++k) {
    int r = 4 * mr + k;
    vx[k] = vy[k] = vz[k] = vw[k] = 0.f;
    bx[k] = by[k] = bz[k] = bw[k] = false;
    int tx = r - u0;
    if (u0 <= Ub && tx >= 0 && tx <= Tb - 1) { vx[k] = LOG2E * lg[((size_t)tx * Up1 + u0) * V]; bx[k] = true; }
    int ty = r - u1;
    if (u1 <= Ub && ty >= 0 && ty <= Tb - 1) { vy[k] = LOG2E * lg[((size_t)ty * Up1 + u1) * V]; by[k] = true; }
    int tz = r - u0 + 1;
    if (u0 >= 1 && u0 <= Ub && tz >= 0 && tz <= Tb - 1) { vz[k] = LOG2E * lg[((size_t)tz * Up1 + (u0 - 1)) * V + labz]; bz[k] = true; }
    int tw = r - u0;
    if (u0 <= Ub - 1 && tw >= 0 && tw <= Tb - 1) { vw[k] = LOG2E * lg[((size_t)tw * Up1 + u0) * V + labw]; bw[k] = true; }
  }
  // shared rounded-mean normalization over the whole macro (4 rows)
  float s_ = 0.f, c_ = 0.f;
#pragma unroll
  for (int k = 0; k < 4; ++k) {
    s_ += (bx[k] ? vx[k] : 0.f) + (by[k] ? vy[k] : 0.f) +
          (bz[k] ? vz[k] : 0.f) + (bw[k] ? vw[k] : 0.f);
    c_ += (float)((int)bx[k] + (int)by[k] + (int)bz[k] + (int)bw[k]);
  }
  for (int off = 32; off; off >>= 1) { s_ += __shfl_xor(s_, off, 64); c_ += __shfl_xor(c_, off, 64); }
  const float m = (c_ > 0.f) ? rintf(s_ / c_) : 0.f;

  float fX[4], fY[4], fZ[4], fW[4];
#pragma unroll
  for (int k = 0; k < 4; ++k) {
    fX[k] = bx[k] ? fexp2(vx[k] - m) : 0.f;
    fY[k] = by[k] ? fexp2(vy[k] - m) : 0.f;
    fZ[k] = bz[k] ? fexp2(vz[k] - m) : 0.f;
    fW[k] = bw[k] ? fexp2(vw[k] - m) : 0.f;
  }

  // 2-step composition (R12-verified): rows i (first) then jj (second)
#define COMP2(P, Q, R_, S, Tc, Uc, i, jj)                                      \
  {                                                                            \
    float y1n = __shfl_up(fY[i], 1, 64);                                       \
    float w1n = __shfl_up(fW[i], 1, 64);                                       \
    double X1 = fX[i], Y1 = fY[i], Z1 = fZ[i], W1 = fW[i];                     \
    double X2 = fX[jj], Y2 = fY[jj], Z2 = fZ[jj], W2 = fW[jj];                 \
    P = X2 * X1; Q = X2 * Z1 + Z2 * (double)y1n; R_ = Z2 * (double)w1n;        \
    S = Y2 * Y1; Tc = W2 * X1 + Y2 * W1; Uc = W2 * Z1;                         \
  }
  double Mp, Mq_, Mr, Ms, Mt, Mu, Np, Nq, Nr, Ns, Nt, Nu;
  COMP2(Mp, Mq_, Mr, Ms, Mt, Mu, 0, 1);
  COMP2(Np, Nq, Nr, Ns, Nt, Nu, 2, 3);
#undef COMP2
  double Mp1 = __shfl_up(Mp, 1, 64), Mq1 = __shfl_up(Mq_, 1, 64);
  double Mr1 = __shfl_up(Mr, 1, 64), Ms1 = __shfl_up(Ms, 1, 64);
  double Mt1 = __shfl_up(Mt, 1, 64), Mu1 = __shfl_up(Mu, 1, 64);

  double dA  = Np * Mp;
  double dB1 = Np * Mq_ + Nq * Ms1;
  double dA1 = Np * Mr + Nq * Mt1 + Nr * Mp1;
  double dB2 = Nq * Mu1 + Nr * Mq1;
  double dA2 = Nr * Mr1;
  double eB  = Ns * Ms;
  double eA  = Ns * Mt + Nt * Mp;
  double eB1 = Ns * Mu + Nt * Mq_ + Nu * Ms1;
  double eA1 = Nt * Mr + Nu * Mt1;
  double eB2 = Nu * Mu1;

  const size_t idx = ((size_t)b * MM4 + mr) * 64 + l;
  g_D1[idx] = make_double2(dA, dB1);
  g_D2[idx] = make_double2(dA1, dB2);
  g_D3[idx] = make_double2(dA2, eB);
  g_D4[idx] = make_double2(eA, eB1);
  g_D5[idx] = make_double2(eA1, eB2);
  if (l == 0) g_mm[b * MM4 + mr] = 4.f * m;
}

__global__ __launch_bounds__(64, 1)
void dp_kernel(const int* __restrict__ logit_len,
               const int* __restrict__ label_len,
               float* __restrict__ out) {
  const int b = blockIdx.x;
  const int lane = threadIdx.x;
  const int Tb = clampi(logit_len[b], 1, T);
  const int Ub = clampi(label_len[b], 1, U);
  const int smax = Tb - 1 + Ub;
  const int Mq = smax >> 2, rem = smax & 3;
  const double2* D1 = g_D1 + (size_t)b * MM4 * 64;
  const double2* D2 = g_D2 + (size_t)b * MM4 * 64;
  const double2* D3 = g_D3 + (size_t)b * MM4 * 64;
  const double2* D4 = g_D4 + (size_t)b * MM4 * 64;
  const double2* D5 = g_D5 + (size_t)b * MM4 * 64;

  double A = (lane == 0) ? 1.0 : 0.0;   // alpha[0][0] = 1 (diag 0 done)
  double Bc = 0.0;

  double2 a1[W], a2[W], a3[W], a4[W], a5[W];
  double2 b1[W], b2[W], b3[W], b4[W], b5[W];
  double2 c1[W], c2[W], c3[W], c4[W], c5[W];

#define LOADG(u1_, u2_, u3_, u4_, u5_, grp)                                    \
  {                                                                            \
    int base_ = (grp) * W;                                                     \
    _Pragma("unroll")                                                          \
    for (int j_ = 0; j_ < W; ++j_) {                                           \
      int m_ = base_ + j_; if (m_ > MM4 - 1) m_ = MM4 - 1;                     \
      u1_[j_] = D1[(size_t)m_ * 64 + lane];                                    \
      u2_[j_] = D2[(size_t)m_ * 64 + lane];                                    \
      u3_[j_] = D3[(size_t)m_ * 64 + lane];                                    \
      u4_[j_] = D4[(size_t)m_ * 64 + lane];                                    \
      u5_[j_] = D5[(size_t)m_ * 64 + lane];                                    \
    }                                                                          \
  }

#define STEPS(u1_, u2_, u3_, u4_, u5_, grp)                                    \
  {                                                                            \
    _Pragma("unroll")                                                          \
    for (int j_ = 0; j_ < W; ++j_) {                                           \
      int m_ = (grp) * W + j_;                                                 \
      if (m_ < Mq) {                                                           \
        double A1s = wave_shr1_f64(A);                                         \
        double B1s = wave_shr1_f64(Bc);                                        \
        double A2s = wave_shr1_f64(A1s);                                       \
        double B2s = wave_shr1_f64(B1s);                                       \
        double na = fma(A, u1_[j_].x, fma(B1s, u1_[j_].y,                      \
                     fma(A1s, u2_[j_].x, fma(B2s, u2_[j_].y,                   \
                         A2s * u3_[j_].x))));                                  \
        double nb = fma(Bc, u3_[j_].y, fma(A, u4_[j_].x,                       \
                     fma(B1s, u4_[j_].y, fma(A1s, u5_[j_].x,                   \
                         B2s * u5_[j_].y))));                                  \
        A = na; Bc = nb;                                                       \
      }                                                                        \
    }                                                                          \
  }

  const int NW = (Mq + W - 1) / W;
  if (NW > 0) {
    LOADG(a1, a2, a3, a4, a5, 0);
    if (NW > 1) LOADG(b1, b2, b3, b4, b5, 1);
    for (int k = 0; k < NW; k += 3) {
      if (k + 2 < NW) LOADG(c1, c2, c3, c4, c5, k + 2);
      STEPS(a1, a2, a3, a4, a5, k);
      if (k + 1 < NW) {
        if (k + 3 < NW) LOADG(a1, a2, a3, a4, a5, k + 3);
        STEPS(b1, b2, b3, b4, b5, k + 1);
        if (k + 2 < NW) {
          if (k + 4 < NW) LOADG(b1, b2, b3, b4, b5, k + 4);
          STEPS(c1, c2, c3, c4, c5, k + 2);
        }
      }
    }
  }
  // tail: rem raw single steps (rows 4Mq .. smax-1)
  for (int j = 0; j < rem; ++j) {
    double2 L1 = g_L1[j][b * 64 + lane];      // {x, z}
    double2 L2 = g_L2[j][b * 64 + lane];      // {y, w}
    double shrB = wave_shr1_f64(Bc);
    double na = fma(A, L1.x, shrB * L1.y);
    double nb = fma(Bc, L2.x, A * L2.y);
    A = na; Bc = nb;
  }

  // answer cell (Tb-1, Ub) produced at step smax
  const int ansLane = Ub >> 1;
  double va = __shfl(A, ansLane, 64);
  double vb = __shfl(Bc, ansLane, 64);
  double v = (Ub & 1) ? vb : va;
  int ev = ((__double2hiint(v) >> 20) & 0x7ff) - 1023;
  double mant = ldexp(v, -ev);

  float msum = 0.f;
  for (int mI = lane; mI < Mq; mI += 64) msum += g_mm[b * MM4 + mI];
  for (int off = 32; off; off >>= 1) msum += __shfl_xor(msum, off, 64);
  for (int j = 0; j < rem; ++j) msum += g_lastm[b][j];

  float lg2 = (float)ev + flog2((float)mant) + msum;

  if (lane == 0) {
    __hip_atomic_store(&g_ps[b], lg2, __ATOMIC_RELEASE, __HIP_MEMORY_SCOPE_AGENT);
    int old = __hip_atomic_fetch_add(&g_ctr, 1, __ATOMIC_ACQ_REL,
                                     __HIP_MEMORY_SCOPE_AGENT);
    if (old == B - 1) {
      float s = 0.0f;
      for (int i = 0; i < B; ++i)
        s += __hip_atomic_load(&g_ps[i], __ATOMIC_ACQUIRE, __HIP_MEMORY_SCOPE_AGENT);
      out[0] = -s * (LN2 / B);
      __hip_atomic_store(&g_ctr, 0, __ATOMIC_RELAXED, __HIP_MEMORY_SCOPE_AGENT);
    }
  }
#undef LOADG
#undef STEPS
}

extern "C" void kernel_launch(void* const* d_in, const int* in_sizes, int n_in,
                              void* d_out, int out_size, void* d_ws, size_t ws_size,
                              hipStream_t stream) {
  const float* logits = (const float*)d_in[0];
  const int* labels = (const int*)d_in[1];
  const int* logit_len = (const int*)d_in[2];
  const int* label_len = (const int*)d_in[3];
  float* out = (float*)d_out;

  hipLaunchKernelGGL(gather_kernel, dim3((MM4 + 3) / 4, B), dim3(256), 0, stream,
                     logits, labels, logit_len, label_len);
  hipLaunchKernelGGL(dp_kernel, dim3(B), dim3(64), 0, stream,
                     logit_len, label_len, out);
}

// Round 14
// 30.420 us; speedup vs baseline: 2.6389x; 1.1471x over previous
//
#include <hip/hip_runtime.h>

// RNNT (Transducer) alpha-recursion loss, forward, mean reduction.
// B=4, T=512, U=100 (U+1=101 cols), V=1024, fp32.
//
// Linear-domain DP (recurrence linear over (+,x)):
//   a[t][u] = a[t-1][u]*fB + a[t][u-1]*fE
// R14 = R13's 4-step fusion with a CHECK-FREE inner loop:
//  - gather writes exact IDENTITY macros (dA=eB=1, rest 0, scale 0) for all
//    macro slots >= Mq, so the DP runs ceil(Mq/W) full groups with NO
//    per-macro bound check and NO load clamp (padded macros are no-ops).
//  - W=4: the 4 loads per array per group sit at immediate offsets
//    0/1024/2048/3072 B (13-bit signed field) -> no per-load address VALU.
//  - effective clock for these tiny dispatches is ~0.6 GHz (fitted across
//    R10/R12/R13), so every issue cycle on the single DP wave is ~1.7ns.
// 4-step map (per lane, Xk = value at lane l-k):
//   A'' = dA*A + dB1*B1 + dA1*A1 + dB2*B2 + dA2*A2
//   B'' = eB*B + eA*A + eB1*B1 + eA1*A1 + eB2*B2
// composed in the WIDE gather from two verified 2-step maps (R12).
// Whole-macro normalization by shared rounded mean m; scales summed
// post-loop. Tail rem=smax&3 raw steps. Two-kernel structure (overlap
// refuted R8/R11).

constexpr int B = 4, T = 512, U = 100, Up1 = 101, V = 1024;
constexpr int DIAGS = T + U;        // 612
constexpr int MM4 = (DIAGS + 3) / 4;  // 153 macro rows (4 diagonals each)
constexpr int W = 4;                // macro-steps per load group (mod-3 pipe)
constexpr float LOG2E = 1.44269504088896340736f;
constexpr float LN2 = 0.69314718055994530942f;

__device__ double2 g_D1[(size_t)B * MM4 * 64];  // {dA,  dB1}
__device__ double2 g_D2[(size_t)B * MM4 * 64];  // {dA1, dB2}
__device__ double2 g_D3[(size_t)B * MM4 * 64];  // {dA2, eB }
__device__ double2 g_D4[(size_t)B * MM4 * 64];  // {eA,  eB1}
__device__ double2 g_D5[(size_t)B * MM4 * 64];  // {eA1, eB2}
__device__ double2 g_L1[3][B * 64];             // tail raw {x,z}
__device__ double2 g_L2[3][B * 64];             // tail raw {y,w}
__device__ float g_mm[B * MM4];                 // per-macro log2 scale (=4m)
__device__ float g_lastm[B][3];                 // tail per-row scales
__device__ float g_ps[B];                       // per-sample log2(alpha)
__device__ int g_ctr = 0;

__device__ __forceinline__ int clampi(int x, int lo, int hi) {
  return x < lo ? lo : (x > hi ? hi : x);
}
__device__ __forceinline__ float fexp2(float x) {
  float r; asm("v_exp_f32 %0, %1" : "=v"(r) : "v"(x)); return r;
}
__device__ __forceinline__ float flog2(float x) {
  float r; asm("v_log_f32 %0, %1" : "=v"(r) : "v"(x)); return r;
}
// whole-wave shift by 1 on a double: lane l receives lane l-1's value
// (lane 0 keeps its own; its coefficients for shifted terms are exact 0)
__device__ __forceinline__ double wave_shr1_f64(double x) {
  int hi = __double2hiint(x), lo = __double2loint(x);
  hi = __builtin_amdgcn_update_dpp(hi, hi, 0x138 /*WF_SR1*/, 0xF, 0xF, false);
  lo = __builtin_amdgcn_update_dpp(lo, lo, 0x138 /*WF_SR1*/, 0xF, 0xF, false);
  return __hiloint2double(hi, lo);
}

__global__ __launch_bounds__(256) void gather_kernel(const float* __restrict__ logits,
                                                     const int* __restrict__ labels,
                                                     const int* __restrict__ logit_len,
                                                     const int* __restrict__ label_len) {
  const int b = blockIdx.y;
  const int mr = blockIdx.x * 4 + (threadIdx.x >> 6);   // macro row index
  const int l = threadIdx.x & 63;
  if (mr >= MM4) return;
  const int Tb = clampi(logit_len[b], 1, T);
  const int Ub = clampi(label_len[b], 1, U);
  const int smax = Tb - 1 + Ub;
  const int Mq = smax >> 2, rem = smax & 3;

  const float* lg = logits + (size_t)b * T * Up1 * V;
  const int u0 = 2 * l, u1 = u0 + 1;
  int labz = 0, labw = 0;
  if (u0 >= 1 && u0 <= U) labz = clampi(labels[b * U + (u0 - 1)], 0, V - 1);
  if (u0 < U)             labw = clampi(labels[b * U + u0], 0, V - 1);

  if (mr >= Mq) {
    // identity macro (numeric no-op) so the DP can run check-free groups
    const size_t idx = ((size_t)b * MM4 + mr) * 64 + l;
    g_D1[idx] = make_double2(1.0, 0.0);
    g_D2[idx] = make_double2(0.0, 0.0);
    g_D3[idx] = make_double2(0.0, 1.0);
    g_D4[idx] = make_double2(0.0, 0.0);
    g_D5[idx] = make_double2(0.0, 0.0);
    if (l == 0) g_mm[b * MM4 + mr] = 0.f;

    if (mr == Mq) {                     // tail rows 4Mq+j, j<rem (raw factors)
      for (int j = 0; j < rem; ++j) {
        int r = 4 * Mq + j;
        float vx = 0.f, vy = 0.f, vz = 0.f, vw = 0.f;
        bool bx = false, by = false, bz = false, bw = false;
        int tx = r - u0;
        if (u0 <= Ub && tx >= 0 && tx <= Tb - 1) { vx = LOG2E * lg[((size_t)tx * Up1 + u0) * V]; bx = true; }
        int ty = r - u1;
        if (u1 <= Ub && ty >= 0 && ty <= Tb - 1) { vy = LOG2E * lg[((size_t)ty * Up1 + u1) * V]; by = true; }
        int tz = r - u0 + 1;
        if (u0 >= 1 && u0 <= Ub && tz >= 0 && tz <= Tb - 1) { vz = LOG2E * lg[((size_t)tz * Up1 + (u0 - 1)) * V + labz]; bz = true; }
        int tw = r - u0;
        if (u0 <= Ub - 1 && tw >= 0 && tw <= Tb - 1) { vw = LOG2E * lg[((size_t)tw * Up1 + u0) * V + labw]; bw = true; }
        float s_ = (bx ? vx : 0.f) + (by ? vy : 0.f) + (bz ? vz : 0.f) + (bw ? vw : 0.f);
        float c_ = (float)((int)bx + (int)by + (int)bz + (int)bw);
        for (int off = 32; off; off >>= 1) { s_ += __shfl_xor(s_, off, 64); c_ += __shfl_xor(c_, off, 64); }
        float m = (c_ > 0.f) ? rintf(s_ / c_) : 0.f;
        g_L1[j][b * 64 + l] = make_double2(bx ? (double)fexp2(vx - m) : 0.0,
                                           bz ? (double)fexp2(vz - m) : 0.0);
        g_L2[j][b * 64 + l] = make_double2(by ? (double)fexp2(vy - m) : 0.0,
                                           bw ? (double)fexp2(vw - m) : 0.0);
        if (l == 0) g_lastm[b][j] = m;
      }
    }
    return;
  }

  // ---- full macro: rows 4mr .. 4mr+3 ----
  float vx[4], vy[4], vz[4], vw[4];
  bool bx[4], by[4], bz[4], bw[4];
#pragma unroll
  for (int k = 0; k < 4; ++k) {
    int r = 4 * mr + k;
    vx[k] = vy[k] = vz[k] = vw[k] = 0.f;
    bx[k] = by[k] = bz[k] = bw[k] = false;
    int tx = r - u0;
    if (u0 <= Ub && tx >= 0 && tx <= Tb - 1) { vx[k] = LOG2E * lg[((size_t)tx * Up1 + u0) * V]; bx[k] = true; }
    int ty = r - u1;
    if (u1 <= Ub && ty >= 0 && ty <= Tb - 1) { vy[k] = LOG2E * lg[((size_t)ty * Up1 + u1) * V]; by[k] = true; }
    int tz = r - u0 + 1;
    if (u0 >= 1 && u0 <= Ub && tz >= 0 && tz <= Tb - 1) { vz[k] = LOG2E * lg[((size_t)tz * Up1 + (u0 - 1)) * V + labz]; bz[k] = true; }
    int tw = r - u0;
    if (u0 <= Ub - 1 && tw >= 0 && tw <= Tb - 1) { vw[k] = LOG2E * lg[((size_t)tw * Up1 + u0) * V + labw]; bw[k] = true; }
  }
  // shared rounded-mean normalization over the whole macro (4 rows)
  float s_ = 0.f, c_ = 0.f;
#pragma unroll
  for (int k = 0; k < 4; ++k) {
    s_ += (bx[k] ? vx[k] : 0.f) + (by[k] ? vy[k] : 0.f) +
          (bz[k] ? vz[k] : 0.f) + (bw[k] ? vw[k] : 0.f);
    c_ += (float)((int)bx[k] + (int)by[k] + (int)bz[k] + (int)bw[k]);
  }
  for (int off = 32; off; off >>= 1) { s_ += __shfl_xor(s_, off, 64); c_ += __shfl_xor(c_, off, 64); }
  const float m = (c_ > 0.f) ? rintf(s_ / c_) : 0.f;

  float fX[4], fY[4], fZ[4], fW[4];
#pragma unroll
  for (int k = 0; k < 4; ++k) {
    fX[k] = bx[k] ? fexp2(vx[k] - m) : 0.f;
    fY[k] = by[k] ? fexp2(vy[k] - m) : 0.f;
    fZ[k] = bz[k] ? fexp2(vz[k] - m) : 0.f;
    fW[k] = bw[k] ? fexp2(vw[k] - m) : 0.f;
  }

  // 2-step composition (R12-verified): rows i (first) then jj (second)
#define COMP2(P, Q, R_, S, Tc, Uc, i, jj)                                      \
  {                                                                            \
    float y1n = __shfl_up(fY[i], 1, 64);                                       \
    float w1n = __shfl_up(fW[i], 1, 64);                                       \
    double X1 = fX[i], Y1 = fY[i], Z1 = fZ[i], W1 = fW[i];                     \
    double X2 = fX[jj], Y2 = fY[jj], Z2 = fZ[jj], W2 = fW[jj];                 \
    P = X2 * X1; Q = X2 * Z1 + Z2 * (double)y1n; R_ = Z2 * (double)w1n;        \
    S = Y2 * Y1; Tc = W2 * X1 + Y2 * W1; Uc = W2 * Z1;                         \
  }
  double Mp, Mq_, Mr, Ms, Mt, Mu, Np, Nq, Nr, Ns, Nt, Nu;
  COMP2(Mp, Mq_, Mr, Ms, Mt, Mu, 0, 1);
  COMP2(Np, Nq, Nr, Ns, Nt, Nu, 2, 3);
#undef COMP2
  double Mp1 = __shfl_up(Mp, 1, 64), Mq1 = __shfl_up(Mq_, 1, 64);
  double Mr1 = __shfl_up(Mr, 1, 64), Ms1 = __shfl_up(Ms, 1, 64);
  double Mt1 = __shfl_up(Mt, 1, 64), Mu1 = __shfl_up(Mu, 1, 64);

  double dA  = Np * Mp;
  double dB1 = Np * Mq_ + Nq * Ms1;
  double dA1 = Np * Mr + Nq * Mt1 + Nr * Mp1;
  double dB2 = Nq * Mu1 + Nr * Mq1;
  double dA2 = Nr * Mr1;
  double eB  = Ns * Ms;
  double eA  = Ns * Mt + Nt * Mp;
  double eB1 = Ns * Mu + Nt * Mq_ + Nu * Ms1;
  double eA1 = Nt * Mr + Nu * Mt1;
  double eB2 = Nu * Mu1;

  const size_t idx = ((size_t)b * MM4 + mr) * 64 + l;
  g_D1[idx] = make_double2(dA, dB1);
  g_D2[idx] = make_double2(dA1, dB2);
  g_D3[idx] = make_double2(dA2, eB);
  g_D4[idx] = make_double2(eA, eB1);
  g_D5[idx] = make_double2(eA1, eB2);
  if (l == 0) g_mm[b * MM4 + mr] = 4.f * m;
}

__global__ __launch_bounds__(64, 1)
void dp_kernel(const int* __restrict__ logit_len,
               const int* __restrict__ label_len,
               float* __restrict__ out) {
  const int b = blockIdx.x;
  const int lane = threadIdx.x;
  const int Tb = clampi(logit_len[b], 1, T);
  const int Ub = clampi(label_len[b], 1, U);
  const int smax = Tb - 1 + Ub;
  const int Mq = smax >> 2, rem = smax & 3;
  // per-lane base pointers; group loads use compile-time offsets j*64
  const double2* D1 = g_D1 + (size_t)b * MM4 * 64 + lane;
  const double2* D2 = g_D2 + (size_t)b * MM4 * 64 + lane;
  const double2* D3 = g_D3 + (size_t)b * MM4 * 64 + lane;
  const double2* D4 = g_D4 + (size_t)b * MM4 * 64 + lane;
  const double2* D5 = g_D5 + (size_t)b * MM4 * 64 + lane;

  double A = (lane == 0) ? 1.0 : 0.0;   // alpha[0][0] = 1 (diag 0 done)
  double Bc = 0.0;

  double2 a1[W], a2[W], a3[W], a4[W], a5[W];
  double2 b1[W], b2[W], b3[W], b4[W], b5[W];
  double2 c1[W], c2[W], c3[W], c4[W], c5[W];

  // group grp covers macros grp*W .. grp*W+W-1; all indices < MM4 by
  // construction (NWC*W <= 152 < 153) and padded macros are identity.
#define LOADG(u1_, u2_, u3_, u4_, u5_, grp)                                    \
  {                                                                            \
    const size_t o_ = (size_t)(grp) * (W * 64);                                \
    _Pragma("unroll")                                                          \
    for (int j_ = 0; j_ < W; ++j_) {                                           \
      u1_[j_] = D1[o_ + j_ * 64];                                              \
      u2_[j_] = D2[o_ + j_ * 64];                                              \
      u3_[j_] = D3[o_ + j_ * 64];                                              \
      u4_[j_] = D4[o_ + j_ * 64];                                              \
      u5_[j_] = D5[o_ + j_ * 64];                                              \
    }                                                                          \
  }

#define STEPS(u1_, u2_, u3_, u4_, u5_)                                         \
  {                                                                            \
    _Pragma("unroll")                                                          \
    for (int j_ = 0; j_ < W; ++j_) {                                           \
      double A1s = wave_shr1_f64(A);                                           \
      double B1s = wave_shr1_f64(Bc);                                          \
      double A2s = wave_shr1_f64(A1s);                                         \
      double B2s = wave_shr1_f64(B1s);                                         \
      double na = fma(A, u1_[j_].x, fma(B1s, u1_[j_].y,                        \
                   fma(A1s, u2_[j_].x, fma(B2s, u2_[j_].y,                     \
                       A2s * u3_[j_].x))));                                    \
      double nb = fma(Bc, u3_[j_].y, fma(A, u4_[j_].x,                         \
                   fma(B1s, u4_[j_].y, fma(A1s, u5_[j_].x,                     \
                       B2s * u5_[j_].y))));                                    \
      A = na; Bc = nb;                                                         \
    }                                                                          \
  }

  const int NWC = (Mq + W - 1) / W;     // full groups (identity-padded)
  if (NWC > 0) {
    LOADG(a1, a2, a3, a4, a5, 0);
    if (NWC > 1) LOADG(b1, b2, b3, b4, b5, 1);
    for (int k = 0; k < NWC; k += 3) {
      if (k + 2 < NWC) LOADG(c1, c2, c3, c4, c5, k + 2);
      STEPS(a1, a2, a3, a4, a5);
      if (k + 1 < NWC) {
        if (k + 3 < NWC) LOADG(a1, a2, a3, a4, a5, k + 3);
        STEPS(b1, b2, b3, b4, b5);
        if (k + 2 < NWC) {
          if (k + 4 < NWC) LOADG(b1, b2, b3, b4, b5, k + 4);
          STEPS(c1, c2, c3, c4, c5);
        }
      }
    }
  }
  // tail: rem raw single steps (rows 4Mq .. smax-1)
  for (int j = 0; j < rem; ++j) {
    double2 L1 = g_L1[j][b * 64 + lane];      // {x, z}
    double2 L2 = g_L2[j][b * 64 + lane];      // {y, w}
    double shrB = wave_shr1_f64(Bc);
    double na = fma(A, L1.x, shrB * L1.y);
    double nb = fma(Bc, L2.x, A * L2.y);
    A = na; Bc = nb;
  }

  // answer cell (Tb-1, Ub) produced at step smax
  const int ansLane = Ub >> 1;
  double va = __shfl(A, ansLane, 64);
  double vb = __shfl(Bc, ansLane, 64);
  double v = (Ub & 1) ? vb : va;
  int ev = ((__double2hiint(v) >> 20) & 0x7ff) - 1023;
  double mant = ldexp(v, -ev);

  float msum = 0.f;
  for (int mI = lane; mI < Mq; mI += 64) msum += g_mm[b * MM4 + mI];
  for (int off = 32; off; off >>= 1) msum += __shfl_xor(msum, off, 64);
  for (int j = 0; j < rem; ++j) msum += g_lastm[b][j];

  float lg2 = (float)ev + flog2((float)mant) + msum;

  if (lane == 0) {
    __hip_atomic_store(&g_ps[b], lg2, __ATOMIC_RELEASE, __HIP_MEMORY_SCOPE_AGENT);
    int old = __hip_atomic_fetch_add(&g_ctr, 1, __ATOMIC_ACQ_REL,
                                     __HIP_MEMORY_SCOPE_AGENT);
    if (old == B - 1) {
      float s = 0.0f;
      for (int i = 0; i < B; ++i)
        s += __hip_atomic_load(&g_ps[i], __ATOMIC_ACQUIRE, __HIP_MEMORY_SCOPE_AGENT);
      out[0] = -s * (LN2 / B);
      __hip_atomic_store(&g_ctr, 0, __ATOMIC_RELAXED, __HIP_MEMORY_SCOPE_AGENT);
    }
  }
#undef LOADG
#undef STEPS
}

extern "C" void kernel_launch(void* const* d_in, const int* in_sizes, int n_in,
                              void* d_out, int out_size, void* d_ws, size_t ws_size,
                              hipStream_t stream) {
  const float* logits = (const float*)d_in[0];
  const int* labels = (const int*)d_in[1];
  const int* logit_len = (const int*)d_in[2];
  const int* label_len = (const int*)d_in[3];
  float* out = (float*)d_out;

  hipLaunchKernelGGL(gather_kernel, dim3((MM4 + 3) / 4, B), dim3(256), 0, stream,
                     logits, labels, logit_len, label_len);
  hipLaunchKernelGGL(dp_kernel, dim3(B), dim3(64), 0, stream,
                     logit_len, label_len, out);
}